// Round 1
// baseline (341.981 us; speedup 1.0000x reference)
//
#include <hip/hip_runtime.h>

// LSTM B=4096, T=512, I=1, H=64, O=1 (fp32 in/out).
// Round 15 experiment: 2-WAVE exchange teams.
//   - MB=4 batches/block, 128 threads (2 waves), grid=1024 (4 blocks/CU).
//   - Each wave owns 32 hidden units (n-cols 32w..32w+31 per gate) ->
//     16 MFMA/wave-step; barrier syncs only 2 waves (was 4).
//   - Batch q lives in A/D row 4q -> every lane owns exactly 2 cells
//     (batch h0, units 32w+l16 and 32w+16+l16): same VALU chain as r14.
//   - K-slot permutation: h stored so a lane's two h values are ADJACENT
//     f16 slots -> one packed ds_write_b32 per lane (was 2 scalar f16).
//     W_hh fragments are loaded with the same slot permutation, so the
//     MFMA contraction over slots == contraction over units.
//     slot sk -> unit u = 32*(sk>>5) + ((sk&31)>>1) + 16*(sk&1).
//   - Quarter-step s_sleep stagger across the 4 co-resident blocks
//     (same-CU set = stride 256 in blockIdx).
// Everything else (exp2-prescaled weights, shared reciprocals, packed
// f32x2 cell math, ci refresh in MFMA shadow, ping-pong h buffers)
// carried over from the 274us round-14 kernel.
// Fallback: if this lands >= 270us, the 4-wave exchange was not the
// latency driver and the session's ~600cyc exchange-floor claim stands.

#define TT   512
#define MB   4
#define HP   72            // f16 row stride (144 B): 16B-aligned, 2-way max
#define BUFE (16 * HP)     // one ping-pong buffer: 16 rows
#define SXP  5             // sh_x row stride (floats)

#define L2E  1.4426950408889634f
#define L2E2 2.8853900817779268f

typedef _Float16 f16x8 __attribute__((ext_vector_type(8)));
typedef _Float16 f16x2 __attribute__((ext_vector_type(2)));
typedef float    f32x4 __attribute__((ext_vector_type(4)));
typedef float    f32x2 __attribute__((ext_vector_type(2)));

#define MFMA16(a, b, c) __builtin_amdgcn_mfma_f32_16x16x32_f16((a), (b), (c), 0, 0, 0)

__device__ __forceinline__ float rcp_(float x)  { return __builtin_amdgcn_rcpf(x); }
__device__ __forceinline__ float exp2_(float x) { return __builtin_amdgcn_exp2f(x); }

__global__ __launch_bounds__(128, 2) void lstm_mfma(
    const float* __restrict__ x,      // [4096, 512]
    const float* __restrict__ w_ih,   // [256]
    const float* __restrict__ w_hh,   // [256, 64]
    const float* __restrict__ b_ih,   // [256]
    const float* __restrict__ b_hh,   // [256]
    const float* __restrict__ w_out,  // [64]
    const float* __restrict__ b_out,  // [1]
    float* __restrict__ out)          // [4096]
{
    __shared__ __align__(16) float    sh_x[TT * SXP];   // [t][q], 10 KB
    __shared__ __align__(16) _Float16 hbuf[2 * BUFE];   // 4.6 KB

    const int tid = threadIdx.x;
    const int w   = tid >> 6;    // wave 0..1 (owns units 32w..32w+31)
    const int L   = tid & 63;
    const int l16 = L & 15;
    const int h0  = L >> 4;      // 0..3 (this lane's batch)
    const int b0  = blockIdx.x * MB;

    // ---- stage x: sh_x[t*SXP + q] = x[b0+q][t] (coalesced) ----
    {
        const int q = tid >> 5;   // batch 0..3
        const int l = tid & 31;
        const float* xr = x + (size_t)(b0 + q) * TT;
        #pragma unroll
        for (int i = 0; i < TT / 32; ++i)
            sh_x[(l + 32 * i) * SXP + q] = xr[l + 32 * i];
    }
    // ---- zero both h buffers (non-4q rows stay zero forever) ----
    for (int i = tid; i < 2 * BUFE; i += 128) hbuf[i] = (_Float16)0.0f;

    // ---- preload W_hh fragments, exp2-prescaled, SLOT-PERMUTED ----
    const float sc[4] = {-L2E, -L2E, L2E2, -L2E};
    f16x8 Bf[4][2][2];            // [gate s][n-tile t][K-chunk kc]
    float wihv[4][2], biasv[4][2];
    #pragma unroll
    for (int s = 0; s < 4; ++s) {
        #pragma unroll
        for (int t = 0; t < 2; ++t) {
            const int n = 64 * s + 32 * w + 16 * t + l16;
            #pragma unroll
            for (int kc = 0; kc < 2; ++kc) {
                f16x8 f;
                #pragma unroll
                for (int i = 0; i < 8; ++i) {
                    const int sk = 8 * h0 + 32 * kc + i;             // k-slot
                    const int u  = 32 * (sk >> 5) + ((sk & 31) >> 1)
                                 + 16 * (sk & 1);                    // unit
                    f[i] = (_Float16)(w_hh[n * 64 + u] * sc[s]);
                }
                Bf[s][t][kc] = f;
            }
            wihv[s][t]  = w_ih[n] * sc[s];
            biasv[s][t] = (b_ih[n] + b_hh[n]) * sc[s];
        }
    }

    // A-frag: row l16, k-slots 8h0..8h0+7 (+32 for chunk 1)
    const int aoff  = l16 * HP + 8 * h0;
    // packed h write: row 4h0, slots {32w+2*l16, +1} = units {32w+l16, +16}
    const int wslot = 4 * h0 * HP + 32 * w + 2 * l16;

    f32x2 ccv = {0.0f, 0.0f};   // c-state of the lane's two cells

    // C-operand pipeline: row 4h0 (elem 0) = x*w_ih+bias for batch h0
    f32x4 ci[4][2];
    {
        const float x0 = sh_x[h0];
        #pragma unroll
        for (int s = 0; s < 4; ++s)
            #pragma unroll
            for (int t = 0; t < 2; ++t) {
                ci[s][t][0] = fmaf(x0, wihv[s][t], biasv[s][t]);
                ci[s][t][1] = 0.0f; ci[s][t][2] = 0.0f; ci[s][t][3] = 0.0f;
            }
    }

    __syncthreads();

    // ---- phase stagger: desync 4 co-resident blocks by quarter-steps ----
    {
        const int ph = (blockIdx.x >> 8) & 3;
        if      (ph == 1) __builtin_amdgcn_s_sleep(4);
        else if (ph == 2) __builtin_amdgcn_s_sleep(8);
        else if (ph == 3) __builtin_amdgcn_s_sleep(12);
    }

    auto step = [&](const _Float16* rb, _Float16* wb, int t) {
        f16x8 a0 = *(const f16x8*)(rb + aoff);
        f16x8 a1 = *(const f16x8*)(rb + aoff + 32);

        f32x4 acc[4][2];
        #pragma unroll
        for (int s = 0; s < 4; ++s)
            #pragma unroll
            for (int u = 0; u < 2; ++u)
                acc[s][u] = MFMA16(a1, Bf[s][u][1], MFMA16(a0, Bf[s][u][0], ci[s][u]));

        // refresh ci for t+1 in the MFMA shadow (h-independent)
        if (t + 1 < TT) {
            const float xn = sh_x[(t + 1) * SXP + h0];
            #pragma unroll
            for (int s = 0; s < 4; ++s) {
                ci[s][0][0] = fmaf(xn, wihv[s][0], biasv[s][0]);
                ci[s][1][0] = fmaf(xn, wihv[s][1], biasv[s][1]);
            }
        }

        // ---- dual-cell update as float2 (cells = units 32w+l16, +16) ----
        f32x2 Ei = {exp2_(acc[0][0][0]), exp2_(acc[0][1][0])};
        f32x2 Ef = {exp2_(acc[1][0][0]), exp2_(acc[1][1][0])};
        f32x2 Eg = {exp2_(acc[2][0][0]), exp2_(acc[2][1][0])};
        f32x2 Eo = {exp2_(acc[3][0][0]), exp2_(acc[3][1][0])};
        f32x2 Di = Ei + 1.0f, Df = Ef + 1.0f, Dg = Eg + 1.0f, Do = Eo + 1.0f;

        f32x2 FG = Df * Dg, IG = Di * Dg, IF = Di * Df;
        f32x2 P  = Di * FG;
        float u  = rcp_(P[0] * P[1]);
        f32x2 inv = {u * P[1], u * P[0]};

        f32x2 si = FG * inv, sf = IG * inv;
        f32x2 tg = 1.0f - 2.0f * (IF * inv);
        ccv = sf * ccv + si * tg;

        f32x2 ca = ccv * L2E2;
        f32x2 Ec = {exp2_(fminf(ca[0], 30.0f)), exp2_(fminf(ca[1], 30.0f))};
        f32x2 Dc = Ec + 1.0f;
        f32x2 Q  = Do * Dc;
        float v  = rcp_(Q[0] * Q[1]);
        f32x2 iq = {v * Q[1], v * Q[0]};
        f32x2 hv = (iq * Dc) * (1.0f - 2.0f * (iq * Do));

        f16x2 hp;
        hp[0] = (_Float16)hv[0];
        hp[1] = (_Float16)hv[1];
        *(f16x2*)(wb + wslot) = hp;          // ONE packed b32 write
        __syncthreads();
    };

    for (int t = 0; t < TT; t += 2) {
        step(hbuf,        hbuf + BUFE, t);      // read buf0, write buf1
        step(hbuf + BUFE, hbuf,        t + 1);  // read buf1, write buf0
    }

    // ---- epilogue: final h in buf0; wave w reduces batches 2w, 2w+1 ----
    // lane L reads slot L of the batch row; unit of slot L:
    const int   uL = 32 * (L >> 5) + ((L & 31) >> 1) + 16 * (L & 1);
    const float wo = w_out[uL];
    #pragma unroll
    for (int p = 0; p < 2; ++p) {
        const int q = 2 * w + p;
        float v = (float)hbuf[(4 * q) * HP + L] * wo;
        #pragma unroll
        for (int off = 32; off; off >>= 1) v += __shfl_down(v, off);
        if (L == 0) out[b0 + q] = v + b_out[0];
    }
}

extern "C" void kernel_launch(void* const* d_in, const int* in_sizes, int n_in,
                              void* d_out, int out_size, void* d_ws, size_t ws_size,
                              hipStream_t stream) {
    const float* x     = (const float*)d_in[0];
    const float* w_ih  = (const float*)d_in[1];
    const float* w_hh  = (const float*)d_in[2];
    const float* b_ih  = (const float*)d_in[3];
    const float* b_hh  = (const float*)d_in[4];
    const float* w_out = (const float*)d_in[5];
    const float* b_out = (const float*)d_in[6];
    float* out = (float*)d_out;

    lstm_mfma<<<4096 / MB, 128, 0, stream>>>(x, w_ih, w_hh, b_ih, b_hh,
                                             w_out, b_out, out);
}

// Round 2
// 265.922 us; speedup vs baseline: 1.2860x; 1.2860x over previous
//
#include <hip/hip_runtime.h>

// LSTM B=4096, T=512, I=1, H=64, O=1 (fp32 in/out).
// Round 16: revert to round-14 structure (session best, 274 us steady) +
// s_setprio(1) around the serial post-MFMA cell-math chain (T5).
// Rationale: r15 (2-wave teams, MB=4) regressed 274->314: MFMA work/CU/step
// is invariant, so MB=4 quadrupled dead-row MFMA issue on the critical path
// while total VALU busy-time stayed 145us (53%x274 == 45.5%x314). The MB
// sweep is complete; MB=8/2-blocks-per-CU/half-step-stagger is the optimum.
// The stagger creates wave role-diversity on each SIMD (one block in its
// serial VALU chain while the co-resident block stalls on ds_read/MFMA),
// which is exactly T5's prerequisite: raise priority for the chain window
// so the latency-critical wave wins issue arbitration.
// Structure: MB=8, grid=512 (2 blocks/CU, s_barrier, ~640-cyc phase stagger).
// h stored plain fp16 in even M rows (row 2q = h[batch q], odd rows zero);
// 8 MFMA/wave-step (16x16x32 f16); all 4 gates of a cell colocated in one
// lane's acc regs (2 cells/lane, zero shuffles); exp2-prescaled weights;
// cross-cell shared reciprocals (6 trans/cell); packed f32x2 cell math;
// x*w_ih+bias enters as the MFMA C operand, refreshed for t+1 in the MFMA
// shadow; one barrier/step; ping-pong h buffers.
// MFMA layouts (m89-verified): A[m=lane&15][k=(lane>>4)*8+i],
// B[k=(lane>>4)*8+i][n=lane&15], D[m=(lane>>4)*4+r][n=lane&15].

#define TT   512
#define MB   8
#define HP   72            // f16 row stride (144 B): 16B-aligned, 2-way max
#define BUFE (16 * HP)     // one ping-pong buffer: 16 rows
#define SXP  10            // sh_x row stride (floats)

#define L2E  1.4426950408889634f
#define L2E2 2.8853900817779268f

typedef _Float16 f16x8 __attribute__((ext_vector_type(8)));
typedef float    f32x4 __attribute__((ext_vector_type(4)));
typedef float    f32x2 __attribute__((ext_vector_type(2)));

#define MFMA16(a, b, c) __builtin_amdgcn_mfma_f32_16x16x32_f16((a), (b), (c), 0, 0, 0)

__device__ __forceinline__ float rcp_(float x)  { return __builtin_amdgcn_rcpf(x); }
__device__ __forceinline__ float exp2_(float x) { return __builtin_amdgcn_exp2f(x); }

__device__ __forceinline__ f16x8 cvt8s(const float4& u0, const float4& u1, float s) {
    f16x8 r;
    r[0] = (_Float16)(u0.x * s); r[1] = (_Float16)(u0.y * s);
    r[2] = (_Float16)(u0.z * s); r[3] = (_Float16)(u0.w * s);
    r[4] = (_Float16)(u1.x * s); r[5] = (_Float16)(u1.y * s);
    r[6] = (_Float16)(u1.z * s); r[7] = (_Float16)(u1.w * s);
    return r;
}

__global__ __launch_bounds__(256, 2) void lstm_mfma(
    const float* __restrict__ x,      // [4096, 512]
    const float* __restrict__ w_ih,   // [256]
    const float* __restrict__ w_hh,   // [256, 64]
    const float* __restrict__ b_ih,   // [256]
    const float* __restrict__ b_hh,   // [256]
    const float* __restrict__ w_out,  // [64]
    const float* __restrict__ b_out,  // [1]
    float* __restrict__ out)          // [4096]
{
    __shared__ __align__(16) float    sh_x[TT * SXP];   // [t][m], 20 KB
    __shared__ __align__(16) _Float16 hbuf[2 * BUFE];   // 4.6 KB

    const int tid = threadIdx.x;
    const int w   = tid >> 6;    // wave 0..3 (owns N-tiles {w, w+4, w+8, w+12})
    const int L   = tid & 63;
    const int l16 = L & 15;
    const int h0  = L >> 4;      // 0..3
    const int b0  = blockIdx.x * MB;
    const int j   = 16 * w + l16;  // hidden unit col owned by this lane

    // ---- stage x: sh_x[t*SXP + m] = x[b0+m][t] (coalesced) ----
    {
        const int q = tid >> 5;   // batch 0..7
        const int l = tid & 31;
        const float* xr = x + (size_t)(b0 + q) * TT;
        #pragma unroll
        for (int i = 0; i < TT / 32; ++i)
            sh_x[(l + 32 * i) * SXP + q] = xr[l + 32 * i];
    }
    // ---- zero both h buffers (odd rows stay zero forever) ----
    for (int i = tid; i < 2 * BUFE; i += 256) hbuf[i] = (_Float16)0.0f;

    // ---- preload W_hh fragments, exp2-prescaled ----
    const float sc[4] = {-L2E, -L2E, L2E2, -L2E};
    f16x8 Bf[4][2];
    float wihv[4], biasv[4];
    #pragma unroll
    for (int s = 0; s < 4; ++s) {
        const int n = 64 * s + j;
        #pragma unroll
        for (int kt = 0; kt < 2; ++kt) {
            const float* p = w_hh + n * 64 + kt * 32 + h0 * 8;
            float4 u0 = *(const float4*)p;
            float4 u1 = *(const float4*)(p + 4);
            Bf[s][kt] = cvt8s(u0, u1, sc[s]);
        }
        wihv[s]  = w_ih[n] * sc[s];
        biasv[s] = (b_ih[n] + b_hh[n]) * sc[s];
    }

    // lane's A row m=l16: batch l16>>1 if l16 even (odd rows zero)
    const int aoff = l16 * HP + h0 * 8;   // f16 units; +32 for K-chunk 1
    // lane's cells: batches 2h0, 2h0+1 -> h rows 4h0 (cell0), 4h0+2 (cell1)
    const int xoff = 2 * h0;
    const int wr   = 4 * h0 * HP + j;

    f32x2 ccv = {0.0f, 0.0f};   // c-state of the lane's two cells

    // C-operand pipeline: rows 0,2 = x*w_ih+bias for batches 2h0, 2h0+1
    f32x4 ci[4];
    {
        const float2 x0 = *(const float2*)(sh_x + xoff);
        #pragma unroll
        for (int s = 0; s < 4; ++s) {
            ci[s][0] = fmaf(x0.x, wihv[s], biasv[s]);
            ci[s][1] = 0.0f;
            ci[s][2] = fmaf(x0.y, wihv[s], biasv[s]);
            ci[s][3] = 0.0f;
        }
    }

    __syncthreads();

    // ---- phase stagger: desync co-resident blocks by ~half a step ----
    if (((blockIdx.x >> 8) ^ blockIdx.x) & 1) {
        __builtin_amdgcn_s_sleep(10);   // ~640 cyc
    }

    auto step = [&](const _Float16* rb, _Float16* wb, int t) {
        f16x8 a0 = *(const f16x8*)(rb + aoff);
        f16x8 a1 = *(const f16x8*)(rb + aoff + 32);

        f32x4 acc[4];
        #pragma unroll
        for (int s = 0; s < 4; ++s)
            acc[s] = MFMA16(a1, Bf[s][1], MFMA16(a0, Bf[s][0], ci[s]));

        // refresh ci for t+1 in the MFMA shadow (h-independent, packed fma)
        if (t + 1 < TT) {
            const float2 xn = *(const float2*)(sh_x + (t + 1) * SXP + xoff);
            const f32x2 xnv = {xn.x, xn.y};
            #pragma unroll
            for (int s = 0; s < 4; ++s) {
                f32x2 c2 = xnv * wihv[s] + biasv[s];   // v_pk_fma_f32
                ci[s][0] = c2[0];
                ci[s][2] = c2[1];
            }
        }

        // ---- T5: favor the serial cell-math chain over the co-resident
        // block's staging-phase waves (role diversity via half-step stagger)
        __builtin_amdgcn_s_setprio(1);

        // ---- dual-cell update as float2 (v_pk_*_f32); trans stay scalar ----
        f32x2 Ei = {exp2_(acc[0][0]), exp2_(acc[0][2])};
        f32x2 Ef = {exp2_(acc[1][0]), exp2_(acc[1][2])};
        f32x2 Eg = {exp2_(acc[2][0]), exp2_(acc[2][2])};
        f32x2 Eo = {exp2_(acc[3][0]), exp2_(acc[3][2])};
        f32x2 Di = Ei + 1.0f, Df = Ef + 1.0f, Dg = Eg + 1.0f, Do = Eo + 1.0f;

        f32x2 FG = Df * Dg, IG = Di * Dg, IF = Di * Df;
        f32x2 P  = Di * FG;
        float u  = rcp_(P[0] * P[1]);
        f32x2 inv = {u * P[1], u * P[0]};

        f32x2 si = FG * inv, sf = IG * inv;
        f32x2 tg = 1.0f - 2.0f * (IF * inv);
        ccv = sf * ccv + si * tg;                       // v_pk_fma_f32

        f32x2 ca = ccv * L2E2;
        f32x2 Ec = {exp2_(fminf(ca[0], 30.0f)), exp2_(fminf(ca[1], 30.0f))};
        f32x2 Dc = Ec + 1.0f;
        f32x2 Q  = Do * Dc;
        float v  = rcp_(Q[0] * Q[1]);
        f32x2 iq = {v * Q[1], v * Q[0]};
        f32x2 hv = (iq * Dc) * (1.0f - 2.0f * (iq * Do));

        wb[wr]          = (_Float16)hv[0];   // row 4h0   (batch 2h0)
        wb[wr + 2 * HP] = (_Float16)hv[1];   // row 4h0+2 (batch 2h0+1)

        __builtin_amdgcn_s_setprio(0);
        __syncthreads();
    };

    for (int t = 0; t < TT; t += 2) {
        step(hbuf,        hbuf + BUFE, t);      // read buf0, write buf1
        step(hbuf + BUFE, hbuf,        t + 1);  // read buf1, write buf0
    }

    // ---- epilogue: final h in buf0; wave w reduces batches 2w, 2w+1 ----
    const float wo = w_out[L];
    #pragma unroll
    for (int p = 0; p < 2; ++p) {
        const int q = 2 * w + p;
        float v = (float)hbuf[(2 * q) * HP + L] * wo;
        #pragma unroll
        for (int off = 32; off; off >>= 1) v += __shfl_down(v, off);
        if (L == 0) out[b0 + q] = v + b_out[0];
    }
}

extern "C" void kernel_launch(void* const* d_in, const int* in_sizes, int n_in,
                              void* d_out, int out_size, void* d_ws, size_t ws_size,
                              hipStream_t stream) {
    const float* x     = (const float*)d_in[0];
    const float* w_ih  = (const float*)d_in[1];
    const float* w_hh  = (const float*)d_in[2];
    const float* b_ih  = (const float*)d_in[3];
    const float* b_hh  = (const float*)d_in[4];
    const float* w_out = (const float*)d_in[5];
    const float* b_out = (const float*)d_in[6];
    float* out = (float*)d_out;

    lstm_mfma<<<4096 / MB, 256, 0, stream>>>(x, w_ih, w_hh, b_ih, b_hh,
                                             w_out, b_out, out);
}